// Round 1
// 328.546 us; speedup vs baseline: 1.0485x; 1.0485x over previous
//
#include <hip/hip_runtime.h>

#define IDIM   256
#define HDIM   64
#define BATCH  1024
#define NITEMS 200
#define NCOLS  (IDIM * HDIM)   // 16384

typedef __bf16 bf16x8 __attribute__((ext_vector_type(8)));
typedef float  f32x4  __attribute__((ext_vector_type(4)));

__device__ __forceinline__ unsigned short f2bf(float f) {
    unsigned int u = __float_as_uint(f);
    u += 0x7FFFu + ((u >> 16) & 1u);   // round-to-nearest-even
    return (unsigned short)(u >> 16);
}

// fast tanh: 1 - 2/(e^{2x}+1); v_exp+v_rcp, saturates correctly (rcp(inf)=0)
__device__ __forceinline__ float fast_tanh(float x) {
    float e2 = __expf(2.0f * x);
    return 1.0f - 2.0f * __builtin_amdgcn_rcpf(e2 + 1.0f);
}

// async global->LDS, 16B per lane; LDS dest must be linear in lane order
#define GLOAD_LDS16(g, l) __builtin_amdgcn_global_load_lds(                 \
    (const __attribute__((address_space(1))) void*)(g),                     \
    (__attribute__((address_space(3))) void*)(l), 16, 0, 0)

// ---- fused prep: blocks [0,4096) transpose Wq f32[k][n] -> Bt bf16[n][k];
//      blocks [4096,4352) convert query f32 -> bf16 (layout unchanged) ----
__global__ __launch_bounds__(256) void k_prep(const float* __restrict__ q,
                                              const float* __restrict__ Wq,
                                              unsigned short* __restrict__ Aq,
                                              unsigned short* __restrict__ Bt) {
    __shared__ float tile[32][33];
    int blk = blockIdx.x;
    int tid = threadIdx.x;
    if (blk >= 4096) {                       // conv branch (block-uniform)
        int idx = (blk - 4096) * 256 + tid;  // 65536 float4s
        float4 f = ((const float4*)q)[idx];
        ushort4 o;
        o.x = f2bf(f.x); o.y = f2bf(f.y); o.z = f2bf(f.z); o.w = f2bf(f.w);
        ((ushort4*)Aq)[idx] = o;
        return;
    }
    int n0 = (blk & 511) * 32;               // 512 n-tiles
    int k0 = (blk >> 9) * 32;                // 8 k-tiles
    int tx = tid & 31;
    int ty = tid >> 5;                       // 0..7
#pragma unroll
    for (int j = 0; j < 32; j += 8)
        tile[ty + j][tx] = Wq[(size_t)(k0 + ty + j) * NCOLS + n0 + tx];
    __syncthreads();
#pragma unroll
    for (int j = 0; j < 32; j += 8)
        Bt[(size_t)(n0 + ty + j) * IDIM + k0 + tx] = f2bf(tile[tx][ty + j]);
}

// ---- m97-style GEMM: P = Aq(1024x256) @ Wq(256x16384), LDS-staged 128x128
//      tile, fused bias+tanh+W_r reduce -> V[b][i] (1024x256 f32).
//      grid: 1024 blocks = 8 m-blocks x 128 n-blocks, 4 waves each;
//      wave w owns the 64(m) x 64(n) quadrant (= all 64 h of one i). ----
__global__ __launch_bounds__(256) void k_gemm_v(const unsigned short* __restrict__ Aq,
                                                const unsigned short* __restrict__ Bt,
                                                const float* __restrict__ bq,
                                                const float* __restrict__ Wr,
                                                float* __restrict__ V) {
    __shared__ __align__(16) unsigned short As[128 * 32];   // [m][k] 8 KB
    __shared__ __align__(16) unsigned short Bs[128 * 32];   // [n][k] 8 KB
    int tid  = threadIdx.x;
    int w    = tid >> 6;
    int lane = tid & 63;
    int l16  = lane & 15;
    int quad = lane >> 4;
    int blk  = blockIdx.x;
    int bn   = blk & 127;                    // 128 n-blocks of 128 cols
    int bm   = blk >> 7;                     // 8 m-blocks of 128 rows

    int m_off  = (w & 1) * 64;
    int n_off  = (w >> 1) * 64;
    int n_base = bn * 128 + n_off;           // multiple of 64
    int icol   = bn * 2 + (w >> 1);          // output column of V, 0..255

    // staging addresses: thread t covers row (t>>2), 16B chunk (t&3); 2 passes
    const unsigned short* Ag = Aq + (size_t)(bm * 128 + (tid >> 2)) * IDIM + (tid & 3) * 8;
    const unsigned short* Bg = Bt + (size_t)(bn * 128 + (tid >> 2)) * IDIM + (tid & 3) * 8;
    unsigned short* Asl = As + tid * 8;      // linear: lane*16B within wave
    unsigned short* Bsl = Bs + tid * 8;

    // fragment read addresses (LDS)
    const unsigned short* Asp = As + (m_off + l16) * 32 + quad * 8;
    const unsigned short* Bsp = Bs + (n_off + l16) * 32 + quad * 8;

    // epilogue operands loaded early (L2-hot, independent of the K-loop)
    float bv[4], wr[4];
#pragma unroll
    for (int nt = 0; nt < 4; nt++) {
        int nl = nt * 16 + l16;
        bv[nt] = bq[n_base + nl];
        wr[nt] = Wr[nl];
    }

    f32x4 acc[4][4] = {};
#pragma unroll
    for (int kk = 0; kk < IDIM; kk += 32) {
        GLOAD_LDS16(Ag + kk,             Asl);
        GLOAD_LDS16(Ag + 64 * IDIM + kk, Asl + 2048);
        GLOAD_LDS16(Bg + kk,             Bsl);
        GLOAD_LDS16(Bg + 64 * IDIM + kk, Bsl + 2048);
        __syncthreads();                      // drains vmcnt -> LDS tile ready
        bf16x8 a[4], b[4];
#pragma unroll
        for (int t = 0; t < 4; t++) a[t] = *(const bf16x8*)(Asp + t * 16 * 32);
#pragma unroll
        for (int t = 0; t < 4; t++) b[t] = *(const bf16x8*)(Bsp + t * 16 * 32);
#pragma unroll
        for (int mt = 0; mt < 4; mt++)
#pragma unroll
            for (int nt = 0; nt < 4; nt++)
                acc[mt][nt] = __builtin_amdgcn_mfma_f32_16x16x32_bf16(a[mt], b[nt], acc[mt][nt], 0, 0, 0);
        __syncthreads();                      // before next-tile overwrite
    }

#pragma unroll
    for (int mt = 0; mt < 4; mt++) {
#pragma unroll
        for (int reg = 0; reg < 4; reg++) {
            float s = 0.0f;
#pragma unroll
            for (int nt = 0; nt < 4; nt++) {
                float c = acc[mt][nt][reg] + bv[nt];
                s += fast_tanh(c) * wr[nt];
            }
            // reduce over the 16 lanes (l16) of this quad-row group
            s += __shfl_xor(s, 1);
            s += __shfl_xor(s, 2);
            s += __shfl_xor(s, 4);
            s += __shfl_xor(s, 8);
            if (l16 == 0) {
                int m = bm * 128 + m_off + mt * 16 + quad * 4 + reg;  // D row = quad*4+reg
                V[m * IDIM + icol] = s;
            }
        }
    }
}

// ---- fused score -> exp -> weighted accumulate, single pass over item ----
// one item per quad (16 lanes), 2 in flight per quad, 8 per wave.
// (UNCHANGED from previous round — bisection control.)
__global__ __launch_bounds__(256) void k_score(const float* __restrict__ item,
                                               const float* __restrict__ V,
                                               float* __restrict__ out) {
    __shared__ float lacc[16][IDIM];   // 16 KB partials
    __shared__ float lS[16];
    int b    = blockIdx.x;
    int tid  = threadIdx.x;
    int wid  = tid >> 6;
    int lane = tid & 63;
    int l16  = lane & 15;
    int quad = lane >> 4;

    const float4* itemB = (const float4*)(item + (size_t)b * NITEMS * IDIM);
    const float4* Vb    = (const float4*)(V + (size_t)b * IDIM);

    float4 v[4];
#pragma unroll
    for (int c = 0; c < 4; c++) v[c] = Vb[l16 + 16 * c];

    float4 acc[4];
#pragma unroll
    for (int c = 0; c < 4; c++) acc[c] = make_float4(0.f, 0.f, 0.f, 0.f);
    float S = 0.f;

    for (int chunk = wid; chunk < 25; chunk += 4) {
        int r0 = chunk * 8 + quad;       // item for x0
        int r1 = r0 + 4;                 // item for x1 (max 199)
        float4 x0[4], x1[4];
#pragma unroll
        for (int c = 0; c < 4; c++) x0[c] = itemB[(size_t)r0 * 64 + l16 + 16 * c];
#pragma unroll
        for (int c = 0; c < 4; c++) x1[c] = itemB[(size_t)r1 * 64 + l16 + 16 * c];

        float d0 = 0.f, d1 = 0.f;
#pragma unroll
        for (int c = 0; c < 4; c++) {
            d0 += x0[c].x * v[c].x + x0[c].y * v[c].y + x0[c].z * v[c].z + x0[c].w * v[c].w;
            d1 += x1[c].x * v[c].x + x1[c].y * v[c].y + x1[c].z * v[c].z + x1[c].w * v[c].w;
        }
#pragma unroll
        for (int m = 1; m < 16; m <<= 1) {
            d0 += __shfl_xor(d0, m);
            d1 += __shfl_xor(d1, m);
        }
        float e0 = __expf(d0);
        float e1 = __expf(d1);
        S += e0 + e1;
#pragma unroll
        for (int c = 0; c < 4; c++) {
            acc[c].x += e0 * x0[c].x + e1 * x1[c].x;
            acc[c].y += e0 * x0[c].y + e1 * x1[c].y;
            acc[c].z += e0 * x0[c].z + e1 * x1[c].z;
            acc[c].w += e0 * x0[c].w + e1 * x1[c].w;
        }
    }

    int row = wid * 4 + quad;            // 16 partial rows
#pragma unroll
    for (int c = 0; c < 4; c++)
        ((float4*)&lacc[row][0])[l16 + 16 * c] = acc[c];
    if (l16 == 0) lS[row] = S;
    __syncthreads();

    float s = 0.f;
#pragma unroll
    for (int i = 0; i < 16; i++) s += lacc[i][tid];
    float Stot = 0.f;
#pragma unroll
    for (int i = 0; i < 16; i++) Stot += lS[i];
    out[(size_t)b * IDIM + tid] = s / (1.0f + Stot);
}

extern "C" void kernel_launch(void* const* d_in, const int* in_sizes, int n_in,
                              void* d_out, int out_size, void* d_ws, size_t ws_size,
                              hipStream_t stream) {
    const float* item  = (const float*)d_in[0];
    const float* query = (const float*)d_in[1];
    const float* Wq    = (const float*)d_in[2];
    const float* bq    = (const float*)d_in[3];
    const float* Wr    = (const float*)d_in[4];
    float* out = (float*)d_out;

    char* ws = (char*)d_ws;
    unsigned short* Aq = (unsigned short*)ws;                          // 512 KB
    unsigned short* Bt = (unsigned short*)(ws + (512 << 10));          // 8 MB
    float*          V  = (float*)(ws + (512 << 10) + (8 << 20));       // 1 MB

    k_prep  <<<4352, 256, 0, stream>>>(query, Wq, Aq, Bt);
    k_gemm_v<<<1024, 256, 0, stream>>>(Aq, Bt, bq, Wr, V);
    k_score <<<1024, 256, 0, stream>>>(item, V, out);
}

// Round 3
// 324.266 us; speedup vs baseline: 1.0623x; 1.0132x over previous
//
#include <hip/hip_runtime.h>

#define IDIM   256
#define HDIM   64
#define BATCH  1024
#define NITEMS 200
#define NCOLS  (IDIM * HDIM)   // 16384

typedef __bf16 bf16x8 __attribute__((ext_vector_type(8)));
typedef float  f32x4  __attribute__((ext_vector_type(4)));

__device__ __forceinline__ unsigned short f2bf(float f) {
    unsigned int u = __float_as_uint(f);
    u += 0x7FFFu + ((u >> 16) & 1u);   // round-to-nearest-even
    return (unsigned short)(u >> 16);
}

// fast tanh: 1 - 2/(e^{2x}+1); v_exp+v_rcp, saturates correctly (rcp(inf)=0)
__device__ __forceinline__ float fast_tanh(float x) {
    float e2 = __expf(2.0f * x);
    return 1.0f - 2.0f * __builtin_amdgcn_rcpf(e2 + 1.0f);
}

// 16-lane (DPP row) rotate-add: ctrl = 0x121/0x122/0x124/0x128 (row_ror:1/2/4/8).
// After all four, every one of the 16 lanes holds the row sum.
// VALU pipe (~5cy/step) instead of ds_swizzle (~25-30cy/step).
template <int CTRL>
__device__ __forceinline__ float row_ror_add(float x) {
    return x + __int_as_float(__builtin_amdgcn_update_dpp(
        0, __float_as_int(x), CTRL, 0xF, 0xF, false));
}
#define ROW_REDUCE16(d)                 \
    d = row_ror_add<0x121>(d);          \
    d = row_ror_add<0x122>(d);          \
    d = row_ror_add<0x124>(d);          \
    d = row_ror_add<0x128>(d);

// async global->LDS, 16B per lane; LDS dest must be linear in lane order
#define GLOAD_LDS16(g, l) __builtin_amdgcn_global_load_lds(                 \
    (const __attribute__((address_space(1))) void*)(g),                     \
    (__attribute__((address_space(3))) void*)(l), 16, 0, 0)

// ---- fused prep: blocks [0,4096) transpose Wq f32[k][n] -> Bt bf16[n][k];
//      blocks [4096,4352) convert query f32 -> bf16 (layout unchanged) ----
__global__ __launch_bounds__(256) void k_prep(const float* __restrict__ q,
                                              const float* __restrict__ Wq,
                                              unsigned short* __restrict__ Aq,
                                              unsigned short* __restrict__ Bt) {
    __shared__ float tile[32][33];
    int blk = blockIdx.x;
    int tid = threadIdx.x;
    if (blk >= 4096) {                       // conv branch (block-uniform)
        int idx = (blk - 4096) * 256 + tid;  // 65536 float4s
        float4 f = ((const float4*)q)[idx];
        ushort4 o;
        o.x = f2bf(f.x); o.y = f2bf(f.y); o.z = f2bf(f.z); o.w = f2bf(f.w);
        ((ushort4*)Aq)[idx] = o;
        return;
    }
    int n0 = (blk & 511) * 32;               // 512 n-tiles
    int k0 = (blk >> 9) * 32;                // 8 k-tiles
    // float4-vectorized tile load: thread covers row tid>>3, 4 cols
    int ty4 = tid >> 3;                      // 0..31
    int tx4 = (tid & 7) * 4;                 // 0,4,...,28
    float4 f = *(const float4*)&Wq[(size_t)(k0 + ty4) * NCOLS + n0 + tx4];
    tile[ty4][tx4 + 0] = f.x; tile[ty4][tx4 + 1] = f.y;
    tile[ty4][tx4 + 2] = f.z; tile[ty4][tx4 + 3] = f.w;
    __syncthreads();
    // transposed write, ushort2 per store (4B/lane, 64B per row segment)
    int txk = (tid & 15) * 2;                // k-pair within tile
    int tyr = tid >> 4;                      // 0..15 (row), +16 second pass
#pragma unroll
    for (int j = 0; j < 32; j += 16) {
        ushort2 o;
        o.x = f2bf(tile[txk][tyr + j]);
        o.y = f2bf(tile[txk + 1][tyr + j]);
        *(ushort2*)&Bt[(size_t)(n0 + tyr + j) * IDIM + k0 + txk] = o;
    }
}

// ---- GEMM: P = Aq(1024x256) @ Wq(256x16384), double-buffered LDS 128x128
//      tile (T3-minimum 2-phase: stage next BEFORE compute current, one
//      barrier per K-step), fused bias+tanh+W_r reduce -> V (1024x256 f32).
__global__ __launch_bounds__(256) void k_gemm_v(const unsigned short* __restrict__ Aq,
                                                const unsigned short* __restrict__ Bt,
                                                const float* __restrict__ bq,
                                                const float* __restrict__ Wr,
                                                float* __restrict__ V) {
    __shared__ __align__(16) unsigned short As[2][128 * 32];   // 2 x 8 KB
    __shared__ __align__(16) unsigned short Bs[2][128 * 32];   // 2 x 8 KB
    int tid  = threadIdx.x;
    int w    = tid >> 6;
    int lane = tid & 63;
    int l16  = lane & 15;
    int quad = lane >> 4;
    int blk  = blockIdx.x;
    int bn   = blk & 127;                    // 128 n-blocks of 128 cols
    int bm   = blk >> 7;                     // 8 m-blocks of 128 rows

    int m_off  = (w & 1) * 64;
    int n_off  = (w >> 1) * 64;
    int n_base = bn * 128 + n_off;           // multiple of 64
    int icol   = bn * 2 + (w >> 1);          // output column of V, 0..255

    // staging addresses: thread t covers row (t>>2), 16B chunk (t&3); 2 halves
    const unsigned short* Ag = Aq + (size_t)(bm * 128 + (tid >> 2)) * IDIM + (tid & 3) * 8;
    const unsigned short* Bg = Bt + (size_t)(bn * 128 + (tid >> 2)) * IDIM + (tid & 3) * 8;

#define STAGE(buf, kk) do {                                                \
        GLOAD_LDS16(Ag + (kk) * 32,             &As[buf][tid * 8]);        \
        GLOAD_LDS16(Ag + 64 * IDIM + (kk) * 32, &As[buf][2048 + tid * 8]); \
        GLOAD_LDS16(Bg + (kk) * 32,             &Bs[buf][tid * 8]);        \
        GLOAD_LDS16(Bg + 64 * IDIM + (kk) * 32, &Bs[buf][2048 + tid * 8]); \
    } while (0)

    // epilogue operands loaded early (L2-hot, independent of the K-loop)
    float bv[4], wr[4];
#pragma unroll
    for (int nt = 0; nt < 4; nt++) {
        int nl = nt * 16 + l16;
        bv[nt] = bq[n_base + nl];
        wr[nt] = Wr[nl];
    }

    f32x4 acc[4][4] = {};
    STAGE(0, 0);
    __syncthreads();                         // buf0 ready
#pragma unroll
    for (int kk = 0; kk < 8; kk++) {
        int cur = kk & 1;
        if (kk < 7) STAGE(cur ^ 1, kk + 1);  // issue-early: latency hides under MFMA
        const unsigned short* Asp = &As[cur][(m_off + l16) * 32 + quad * 8];
        const unsigned short* Bsp = &Bs[cur][(n_off + l16) * 32 + quad * 8];
        bf16x8 a[4], b[4];
#pragma unroll
        for (int t = 0; t < 4; t++) a[t] = *(const bf16x8*)(Asp + t * 16 * 32);
#pragma unroll
        for (int t = 0; t < 4; t++) b[t] = *(const bf16x8*)(Bsp + t * 16 * 32);
#pragma unroll
        for (int mt = 0; mt < 4; mt++)
#pragma unroll
            for (int nt = 0; nt < 4; nt++)
                acc[mt][nt] = __builtin_amdgcn_mfma_f32_16x16x32_bf16(a[mt], b[nt], acc[mt][nt], 0, 0, 0);
        __syncthreads();                     // drains vmcnt (next buf ready) + read-before-overwrite safety
    }
#undef STAGE

    int i = icol;
#pragma unroll
    for (int mt = 0; mt < 4; mt++) {
#pragma unroll
        for (int reg = 0; reg < 4; reg++) {
            float s = 0.0f;
#pragma unroll
            for (int nt = 0; nt < 4; nt++) {
                float c = acc[mt][nt][reg] + bv[nt];
                s += fast_tanh(c) * wr[nt];
            }
            ROW_REDUCE16(s);                 // DPP rotate-reduce over l16
            if (l16 == 0) {
                int m = bm * 128 + m_off + mt * 16 + quad * 4 + reg;
                V[m * IDIM + i] = s;
            }
        }
    }
}

// ---- fused score -> exp -> weighted accumulate, single pass over item ----
// one item per quad (16 lanes), 2 in flight per quad, 8 per wave.
__global__ __launch_bounds__(256) void k_score(const float* __restrict__ item,
                                               const float* __restrict__ V,
                                               float* __restrict__ out) {
    __shared__ float lacc[16][IDIM];   // 16 KB partials
    __shared__ float lS[16];
    int b    = blockIdx.x;
    int tid  = threadIdx.x;
    int wid  = tid >> 6;
    int lane = tid & 63;
    int l16  = lane & 15;
    int quad = lane >> 4;

    const float4* itemB = (const float4*)(item + (size_t)b * NITEMS * IDIM);
    const float4* Vb    = (const float4*)(V + (size_t)b * IDIM);

    float4 v[4];
#pragma unroll
    for (int c = 0; c < 4; c++) v[c] = Vb[l16 + 16 * c];

    float4 acc[4];
#pragma unroll
    for (int c = 0; c < 4; c++) acc[c] = make_float4(0.f, 0.f, 0.f, 0.f);
    float S = 0.f;

    for (int chunk = wid; chunk < 25; chunk += 4) {
        int r0 = chunk * 8 + quad;       // item for x0
        int r1 = r0 + 4;                 // item for x1 (max 199)
        float4 x0[4], x1[4];
#pragma unroll
        for (int c = 0; c < 4; c++) x0[c] = itemB[(size_t)r0 * 64 + l16 + 16 * c];
#pragma unroll
        for (int c = 0; c < 4; c++) x1[c] = itemB[(size_t)r1 * 64 + l16 + 16 * c];

        float d0 = 0.f, d1 = 0.f;
#pragma unroll
        for (int c = 0; c < 4; c++) {
            d0 += x0[c].x * v[c].x + x0[c].y * v[c].y + x0[c].z * v[c].z + x0[c].w * v[c].w;
            d1 += x1[c].x * v[c].x + x1[c].y * v[c].y + x1[c].z * v[c].z + x1[c].w * v[c].w;
        }
        // 16-lane reduce on the VALU pipe (DPP) instead of 8 serial ds_swizzles
        ROW_REDUCE16(d0);
        ROW_REDUCE16(d1);
        float e0 = __expf(d0);
        float e1 = __expf(d1);
        S += e0 + e1;
#pragma unroll
        for (int c = 0; c < 4; c++) {
            acc[c].x += e0 * x0[c].x + e1 * x1[c].x;
            acc[c].y += e0 * x0[c].y + e1 * x1[c].y;
            acc[c].z += e0 * x0[c].z + e1 * x1[c].z;
            acc[c].w += e0 * x0[c].w + e1 * x1[c].w;
        }
    }

    int row = wid * 4 + quad;            // 16 partial rows
#pragma unroll
    for (int c = 0; c < 4; c++)
        ((float4*)&lacc[row][0])[l16 + 16 * c] = acc[c];
    if (l16 == 0) lS[row] = S;
    __syncthreads();

    float s = 0.f;
#pragma unroll
    for (int i = 0; i < 16; i++) s += lacc[i][tid];
    float Stot = 0.f;
#pragma unroll
    for (int i = 0; i < 16; i++) Stot += lS[i];
    out[(size_t)b * IDIM + tid] = s / (1.0f + Stot);
}

extern "C" void kernel_launch(void* const* d_in, const int* in_sizes, int n_in,
                              void* d_out, int out_size, void* d_ws, size_t ws_size,
                              hipStream_t stream) {
    const float* item  = (const float*)d_in[0];
    const float* query = (const float*)d_in[1];
    const float* Wq    = (const float*)d_in[2];
    const float* bq    = (const float*)d_in[3];
    const float* Wr    = (const float*)d_in[4];
    float* out = (float*)d_out;

    char* ws = (char*)d_ws;
    unsigned short* Aq = (unsigned short*)ws;                          // 512 KB
    unsigned short* Bt = (unsigned short*)(ws + (512 << 10));          // 8 MB
    float*          V  = (float*)(ws + (512 << 10) + (8 << 20));       // 1 MB

    k_prep  <<<4352, 256, 0, stream>>>(query, Wq, Aq, Bt);
    k_gemm_v<<<1024, 256, 0, stream>>>(Aq, Bt, bq, Wr, V);
    k_score <<<1024, 256, 0, stream>>>(item, V, out);
}